// Round 8
// baseline (261.655 us; speedup 1.0000x reference)
//
#include <hip/hip_runtime.h>
#include <cstdint>
#include <cstddef>

typedef unsigned short u16;
typedef unsigned int   u32;

typedef __bf16 bf8   __attribute__((ext_vector_type(8)));
typedef float  f32x4 __attribute__((ext_vector_type(4)));

__device__ __forceinline__ float b2f(u16 v) {
  union { u32 i; float f; } c; c.i = ((u32)v) << 16; return c.f;
}
__device__ __forceinline__ u16 f2b(float f) {
  union { u32 i; float f; } c; c.f = f;
  u32 x = c.i;
  u32 r = (x + 0x7FFFu + ((x >> 16) & 1u)) >> 16;
  return (u16)r;
}
__device__ __forceinline__ float sigf(float x) { return 1.0f / (1.0f + __expf(-x)); }
__device__ __forceinline__ float tanhfast(float x) { return 2.0f * sigf(2.0f * x) - 1.0f; }

// convert 8 consecutive floats to a bf16x8 fragment (RNE)
__device__ __forceinline__ bf8 cvt8(const float* __restrict__ p) {
  f32x4 lo = *(const f32x4*)p;
  f32x4 hi = *(const f32x4*)(p + 4);
  union { u16 s[8]; bf8 v; } c;
#pragma unroll
  for (int i = 0; i < 4; ++i) { c.s[i] = f2b(lo[i]); c.s[4 + i] = f2b(hi[i]); }
  return c.v;
}

// async 16B global -> LDS (dest = wave-uniform base + lane*16)
__device__ __forceinline__ void ld_lds16(const u16* g, u16* l) {
  __builtin_amdgcn_global_load_lds((const __attribute__((address_space(1))) void*)g,
                                   (__attribute__((address_space(3))) void*)l, 16, 0, 0);
}

#define CSR_STRIDE 80

// ---- weight repack: W fp32 [K x 128] -> Bt bf16 in MFMA-fragment order ----
// frag id f = (hh*4+ks)*512 + c*64 + lane ; element j in [0,8):
//   Bt[f*8+j] = bf16( W[(hh*128+ks*32+quad*8+j)*128 + (c*16+ln)] )   (lane=quad*16+ln)
// blocks >= 64 zero the degree-count array instead.
__global__ __launch_bounds__(256) void k_transpose(
    const float* __restrict__ W0, const float* __restrict__ W1,
    const float* __restrict__ W2, const float* __restrict__ W3,
    const float* __restrict__ W4,
    u16* __restrict__ B0, u16* __restrict__ B1, u16* __restrict__ B2,
    u16* __restrict__ B3, u16* __restrict__ B4,
    int* __restrict__ cnt, int N) {
  if (blockIdx.x >= 64) {
    int i = (blockIdx.x - 64) * 256 + threadIdx.x;
    if (i < N) cnt[i] = 0;
    return;
  }
  int t = blockIdx.x * 256 + threadIdx.x;
  const float* in; u16* out; int f;
  if (t < 2048)       { in = W0; out = B0; f = t; }
  else if (t < 4096)  { in = W1; out = B1; f = t - 2048; }
  else if (t < 8192)  { in = W2; out = B2; f = t - 4096; }
  else if (t < 12288) { in = W3; out = B3; f = t - 8192; }
  else                { in = W4; out = B4; f = t - 12288; }
  int ln = f & 15, quad = (f >> 4) & 3, c = (f >> 6) & 7, ks = (f >> 9) & 3, hh = f >> 11;
  int n = c * 16 + ln;
  int k0 = hh * 128 + ks * 32 + quad * 8;
  union { u16 s[8]; uint4 q; } tmp;
#pragma unroll
  for (int j = 0; j < 8; ++j) tmp.s[j] = f2b(in[(size_t)(k0 + j) * 128 + n]);
  *(uint4*)(out + (size_t)f * 8) = tmp.q;
}

// ---------------- CSR build: one pass; cnt doubles as cursor and final degree ----------------
__global__ void k_fill(const int* __restrict__ src, const int* __restrict__ dst,
                       int* __restrict__ cnt, int* __restrict__ csr, int E) {
  int e = blockIdx.x * 256 + threadIdx.x;
  if (e < E) {
    int d = dst[e];
    int pos = atomicAdd(&cnt[d], 1);
    if (pos < CSR_STRIDE) csr[(size_t)d * CSR_STRIDE + pos] = src[e];
  }
}

// ---------------- aggregation: one wave per node, 4 edges x 16-lane x 16B ----------------
// out[d] = postproc( rsqrt(deg+1) * (sum_{s->d} y[s] + y[d]) + bias )
__global__ __launch_bounds__(256) void k_agg(const u16* __restrict__ y,
                                             const int* __restrict__ cnt,
                                             const int* __restrict__ csr,
                                             const float* __restrict__ bias,
                                             u16* __restrict__ out, int relu, int N) {
  int wv = (blockIdx.x * 256 + threadIdx.x) >> 6;
  int lane = threadIdx.x & 63;
  if (wv >= N) return;
  int g = lane >> 4, t = lane & 15;
  const uint4* yq = (const uint4*)y;        // 16 uint4 per 128-feat bf16 row
  int deg = cnt[wv];
  int degc = (deg < 64) ? deg : 64;
  long base = (long)wv * CSR_STRIDE;
  int myidx = (lane < degc) ? csr[base + lane] : 0;

  float a[8];
#pragma unroll
  for (int j = 0; j < 8; ++j) a[j] = 0.0f;

  for (int b = 0; b < degc; b += 8) {
    int e0 = b + g, e1 = b + 4 + g;
    int s0 = __shfl(myidx, (e0 < degc) ? e0 : 0, 64);
    int s1 = __shfl(myidx, (e1 < degc) ? e1 : 0, 64);
    uint4 v0 = yq[(size_t)s0 * 16 + t];
    uint4 v1 = yq[(size_t)s1 * 16 + t];
    if (e0 < degc) {
      const u32* w = (const u32*)&v0;
#pragma unroll
      for (int i = 0; i < 4; ++i) { a[2*i] += b2f((u16)(w[i] & 0xFFFF)); a[2*i+1] += b2f((u16)(w[i] >> 16)); }
    }
    if (e1 < degc) {
      const u32* w = (const u32*)&v1;
#pragma unroll
      for (int i = 0; i < 4; ++i) { a[2*i] += b2f((u16)(w[i] & 0xFFFF)); a[2*i+1] += b2f((u16)(w[i] >> 16)); }
    }
  }
  // cross-group reduction: groups 0..3 hold partial sums of the same feature slice
#pragma unroll
  for (int j = 0; j < 8; ++j) {
    a[j] += __shfl_xor(a[j], 16, 64);
    a[j] += __shfl_xor(a[j], 32, 64);
  }
  if (g == 0) {
    // rare tail deg in (64, 80): add serially (16 lanes do full rows)
    int degt = (deg < CSR_STRIDE) ? deg : CSR_STRIDE;
    for (int p = 64; p < degt; ++p) {
      int s = csr[base + p];
      uint4 v = yq[(size_t)s * 16 + t];
      const u32* w = (const u32*)&v;
#pragma unroll
      for (int i = 0; i < 4; ++i) { a[2*i] += b2f((u16)(w[i] & 0xFFFF)); a[2*i+1] += b2f((u16)(w[i] >> 16)); }
    }
    // self-loop
    uint4 sv = yq[(size_t)wv * 16 + t];
    const u32* w = (const u32*)&sv;
#pragma unroll
    for (int i = 0; i < 4; ++i) { a[2*i] += b2f((u16)(w[i] & 0xFFFF)); a[2*i+1] += b2f((u16)(w[i] >> 16)); }
    float di = rsqrtf((float)deg + 1.0f);
    f32x4 b0 = *(const f32x4*)(bias + t * 8);
    f32x4 b1 = *(const f32x4*)(bias + t * 8 + 4);
    union { u16 s[8]; uint4 q; } o;
#pragma unroll
    for (int j = 0; j < 8; ++j) {
      float r = di * a[j] + ((j < 4) ? b0[j] : b1[j - 4]);
      if (relu) r = fmaxf(r, 0.0f);
      o.s[j] = f2b(r);
    }
    ((uint4*)out)[(size_t)wv * 16 + t] = o.q;
  }
}

// ---------------- layer GEMM: y[M,128] = bf16( (A[M,128] @ W) * rsqrt(deg+1)[row] ) ----------------
template <bool AF>   // A is fp32 (convert) or bf16
__global__ __launch_bounds__(256) void k_gemm(
    const void* __restrict__ Av,
    const u16* __restrict__ Bt,          // fragment-ordered, 16384 u16
    const int* __restrict__ cnt,
    u16* __restrict__ outb, int M) {
  __shared__ __align__(16) u16 bs[16384];
  int tid = threadIdx.x;
  int lane = tid & 63, wave = tid >> 6;
  int ln = lane & 15, quad = lane >> 4;
  int rowbase = blockIdx.x * 64 + wave * 16;
  int rowA = rowbase + ln;
  long rA = (rowA < M) ? rowA : (M - 1);

  {
    const u16* g = Bt + wave * 4096 + lane * 8;
    u16* l = bs + wave * 4096;
#pragma unroll
    for (int i = 0; i < 8; ++i) ld_lds16(g + i * 512, l + i * 512);
  }

  bf8 af[4];
#pragma unroll
  for (int ks = 0; ks < 4; ++ks) {
    int kk = ks * 32 + quad * 8;
    if (AF) af[ks] = cvt8((const float*)Av + rA * 128 + kk);
    else    af[ks] = *(const bf8*)((const u16*)Av + rA * 128 + kk);
  }

  f32x4 acc[8];
#pragma unroll
  for (int c = 0; c < 8; ++c) { acc[c][0] = 0.f; acc[c][1] = 0.f; acc[c][2] = 0.f; acc[c][3] = 0.f; }

  __syncthreads();   // drains the async LDS DMA
#pragma unroll
  for (int ks = 0; ks < 4; ++ks) {
#pragma unroll
    for (int c = 0; c < 8; ++c) {
      bf8 bfr = *(const bf8*)(bs + ks * 4096 + c * 512 + lane * 8);
      acc[c] = __builtin_amdgcn_mfma_f32_16x16x32_bf16(af[ks], bfr, acc[c], 0, 0, 0);
    }
  }

  int rb = rowbase + quad * 4;
  float rs[4];
#pragma unroll
  for (int r = 0; r < 4; ++r) {
    int row = rb + r;
    rs[r] = (row < M) ? rsqrtf((float)cnt[row] + 1.0f) : 0.0f;
  }
#pragma unroll
  for (int c = 0; c < 8; ++c) {
    int col = c * 16 + ln;
#pragma unroll
    for (int r = 0; r < 4; ++r) {
      int row = rb + r;
      if (row < M) outb[(size_t)row * 128 + col] = f2b(acc[c][r] * rs[r]);
    }
  }
}

// ---------------- fused GRU v8: 1-wave blocks, zero barriers, RACE-FIXED refill ----
// out = (1-u)*h + u*tanh([emb | sig(r)*h] @ Wc + bc); u = sig([emb|h]@Wz+bz)
// v7 diverged under graph replay: each iteration refills the slot it JUST read, and
// hipcc may sink the MFMA (register-only, rule #18) past the global_load_lds issue, so
// the slot's ds_reads were only ISSUED -- not complete -- when the DMA overwrite
// launched. Timing-dependent corruption. FIX: before every refill, force this wave's
// LDS reads architecturally complete: s_waitcnt lgkmcnt(0) + sched_barrier(0). Cost ~0
// (lgkmcnt is already 0 for the MFMA operands); sched_barrier pins the order.
// vmcnt ledger (8 DMA/stage, VMEM loads retire in issue order): steady-state
// vmcnt(8) leaves exactly the NEWEST stage (next chunk) in flight; older A-frag/hc
// loads ahead in the queue can only cause over-wait, never under-wait. Last c-chunk
// uses vmcnt(0). LDS 20 KB -> 8 independent 1-wave blocks/CU; no s_barrier anywhere.
__global__ __launch_bounds__(64, 2) void k_gru(
    const u16* __restrict__ emb, const float* __restrict__ h,
    const u16* __restrict__ Btz, const u16* __restrict__ Btr, const u16* __restrict__ Btc,
    const float* __restrict__ bz, const float* __restrict__ br, const float* __restrict__ bc,
    float* __restrict__ out, int M) {
  __shared__ __align__(16) u16 lds[10240];   // 16 KB ring + 4 KB at = 20 KB
  int lane = threadIdx.x;                    // one wave per block
  int ln = lane & 15, quad = lane >> 4;
  int rowbase = blockIdx.x * 16;
  int rowA = rowbase + ln;
  long rA = (rowA < M) ? rowA : (M - 1);
  int rb = rowbase + quad * 4;
  u16* const atw = lds + 8192;               // 16x128 rh tile (XOR-swizzled)

  // stage one full 8 KB chunk into ring slot s: 8 DMA instrs (this wave alone)
  auto stage = [&](const u16* src, int s) {
#pragma unroll
    for (int i = 0; i < 8; ++i)
      ld_lds16(src + i * 512 + lane * 8, &lds[s * 4096 + i * 512]);
  };
  // fence: this wave's outstanding LDS reads complete before any refill DMA issues
  auto lds_fence = [&]() {
    asm volatile("s_waitcnt lgkmcnt(0)" ::: "memory");
    __builtin_amdgcn_sched_barrier(0);
  };

  // A fragments (issued before stages; older in the vmcnt queue)
  bf8 af_e[4], af_h[4];
#pragma unroll
  for (int ks = 0; ks < 4; ++ks)
    af_e[ks] = *(const bf8*)(emb + rA * 128 + ks * 32 + quad * 8);
#pragma unroll
  for (int ks = 0; ks < 4; ++ks)
    af_h[ks] = cvt8(h + rA * 128 + ks * 32 + quad * 8);

  // depth-1 prefetch: chunks t=0 (z ks0) and t=1 (r ks0)
  stage(Btz, 0);
  stage(Btr, 1);

  f32x4 accz[8], accr[8];
#pragma unroll
  for (int c = 0; c < 8; ++c) {
    accz[c][0] = 0.f; accz[c][1] = 0.f; accz[c][2] = 0.f; accz[c][3] = 0.f;
    accr[c][0] = 0.f; accr[c][1] = 0.f; accr[c][2] = 0.f; accr[c][3] = 0.f;
  }

  // z/r pass: 16 thin chunks (z,r alternate per ks); slot = t&1
#pragma unroll
  for (int t = 0; t < 16; ++t) {
    asm volatile("s_waitcnt vmcnt(8)" ::: "memory");   // chunk t landed; t+1 in flight
    int ks = t >> 1;
    bf8 af = (ks < 4) ? af_e[ks] : af_h[ks - 4];
    int s = t & 1;
    f32x4* acc = (t & 1) ? accr : accz;                // t unrolled -> static
#pragma unroll
    for (int c = 0; c < 8; ++c) {
      bf8 bfr = *(const bf8*)(&lds[s * 4096 + (c * 64 + lane) * 8]);
      acc[c] = __builtin_amdgcn_mfma_f32_16x16x32_bf16(af, bfr, acc[c], 0, 0, 0);
    }
    lds_fence();                                       // reads done -> slot safe to refill
    if (t < 14) {
      int tn = t + 2;
      stage(((tn & 1) ? Btr : Btz) + (tn >> 1) * 4096, tn & 1);
    } else if (t == 14) {
      stage(Btc, 0);                                   // c chunk 0 -> slot0
    } else {
      stage(Btc + 4096, 1);                            // c chunk 1 -> slot1
    }
  }

  // h at C-layout positions (for rh and final blend) — registers; c0/c1 DMA hides here
  f32x4 hc[8];
#pragma unroll
  for (int c = 0; c < 8; ++c) {
    int col = c * 16 + ln;
#pragma unroll
    for (int r = 0; r < 4; ++r) {
      int row = rb + r;
      hc[c][r] = (row < M) ? h[(size_t)row * 128 + col] : 0.0f;
    }
  }

  // u = sigmoid(accz+bz); rh = sigmoid(accr+br)*h -> wave-private at tile (XOR swizzle)
#pragma unroll
  for (int c = 0; c < 8; ++c) {
    int col = c * 16 + ln;
    float bzc = bz[col], brc = br[col];
#pragma unroll
    for (int r = 0; r < 4; ++r) {
      float uu = sigf(accz[c][r] + bzc);
      float rr = sigf(accr[c][r] + brc);
      accz[c][r] = uu;                       // keep u in registers
      int wl = quad * 4 + r;                 // wave-local row 0..15
      int idx = (wl * 128 + col) ^ ((wl & 7) << 3);
      atw[idx] = f2b(rr * hc[c][r]);
      accr[c][r] = 0.0f;                     // accr becomes candidate accumulator
    }
  }
  // wave-private transpose readback: same-wave LDS RAW, ordered via lgkmcnt (no barrier)
  bf8 af_at[4];
#pragma unroll
  for (int ks = 0; ks < 4; ++ks) {
    int wl = ln;
    int idx = (wl * 128 + ks * 32 + quad * 8) ^ ((wl & 7) << 3);
    af_at[ks] = *(const bf8*)(&atw[idx]);
  }

  // candidate pass: 8 chunks, slot = j&1
#pragma unroll
  for (int j = 0; j < 8; ++j) {
    if (j < 7) asm volatile("s_waitcnt vmcnt(8)" ::: "memory");
    else       asm volatile("s_waitcnt vmcnt(0)" ::: "memory");
    bf8 af = (j < 4) ? af_e[j] : af_at[j - 4];
    int s = j & 1;
#pragma unroll
    for (int c = 0; c < 8; ++c) {
      bf8 bfr = *(const bf8*)(&lds[s * 4096 + (c * 64 + lane) * 8]);
      accr[c] = __builtin_amdgcn_mfma_f32_16x16x32_bf16(af, bfr, accr[c], 0, 0, 0);
    }
    if (j < 6) {
      lds_fence();                                     // reads done -> slot safe to refill
      stage(Btc + (size_t)(j + 2) * 4096, j & 1);
    }
  }

  // epilogue: out = (1-u)*h + u*tanh(accc + bc)
#pragma unroll
  for (int c = 0; c < 8; ++c) {
    int col = c * 16 + ln;
    float bcc = bc[col];
#pragma unroll
    for (int r = 0; r < 4; ++r) {
      int row = rb + r;
      if (row < M) {
        float cd = tanhfast(accr[c][r] + bcc);
        float uu = accz[c][r];
        out[(size_t)row * 128 + col] = (1.0f - uu) * hc[c][r] + uu * cd;
      }
    }
  }
}

extern "C" void kernel_launch(void* const* d_in, const int* in_sizes, int n_in,
                              void* d_out, int out_size, void* d_ws, size_t ws_size,
                              hipStream_t stream) {
  const float* x     = (const float*)d_in[0];
  const float* h     = (const float*)d_in[1];
  const int*   ei    = (const int*)d_in[2];
  const float* W_in  = (const float*)d_in[3];
  const float* b_in  = (const float*)d_in[4];
  const float* W_hid = (const float*)d_in[5];
  const float* b_hid = (const float*)d_in[6];
  const float* W_z   = (const float*)d_in[7];
  const float* b_z   = (const float*)d_in[8];
  const float* W_r   = (const float*)d_in[9];
  const float* b_r   = (const float*)d_in[10];
  const float* W_c   = (const float*)d_in[11];
  const float* b_c   = (const float*)d_in[12];

  const int N = in_sizes[0] / 128;
  const int E = in_sizes[2] / 2;
  const int* src = ei;
  const int* dst = ei + E;

  char* p = (char*)d_ws;
  auto carve = [&](size_t bytes) { char* r = p; p += (bytes + 255) & ~(size_t)255; return r; };
  u16* Bt_in   = (u16*)carve((size_t)16384 * 2);
  u16* Bt_hid  = (u16*)carve((size_t)16384 * 2);
  u16* Bt_z    = (u16*)carve((size_t)32768 * 2);
  u16* Bt_r    = (u16*)carve((size_t)32768 * 2);
  u16* Bt_c    = (u16*)carve((size_t)32768 * 2);
  int* cnt  = (int*)carve((size_t)N * 4);
  int* csr  = (int*)carve((size_t)N * CSR_STRIDE * 4);
  u16* y    = (u16*)carve((size_t)N * 128 * 2);    // bf16 intermediates
  u16* h1   = (u16*)carve((size_t)N * 128 * 2);
  u16* emb  = (u16*)carve((size_t)N * 128 * 2);

  int gN = (N + 255) / 256;
  int gE = (E + 255) / 256;
  int gG = (N + 63) / 64;      // GEMM: 64 rows per block
  int gW = (N + 15) / 16;      // GRU: 16 rows per 1-wave block
  int gA = (N + 3) / 4;        // AGG: 4 waves (nodes) per block

  k_transpose<<<64 + gN, 256, 0, stream>>>(W_in, W_hid, W_z, W_r, W_c,
                                           Bt_in, Bt_hid, Bt_z, Bt_r, Bt_c, cnt, N);
  k_fill<<<gE, 256, 0, stream>>>(src, dst, cnt, csr, E);

  // layer 1: y = (x @ W_in) * dinv ; h1 = relu(dinv * agg(y) + b_in)
  k_gemm<true><<<gG, 256, 0, stream>>>(x, Bt_in, cnt, y, N);
  k_agg<<<gA, 256, 0, stream>>>(y, cnt, csr, b_in, h1, 1, N);
  // layer 2: y = (h1 @ W_hid) * dinv ; emb = dinv * agg(y) + b_hid
  k_gemm<false><<<gG, 256, 0, stream>>>(h1, Bt_hid, cnt, y, N);
  k_agg<<<gA, 256, 0, stream>>>(y, cnt, csr, b_hid, emb, 0, N);
  // fused GRU: 1-wave blocks, no barriers
  k_gru<<<gW, 64, 0, stream>>>(emb, h, Bt_z, Bt_r, Bt_c, b_z, b_r, b_c, (float*)d_out, N);
}

// Round 10
// 252.908 us; speedup vs baseline: 1.0346x; 1.0346x over previous
//
#include <hip/hip_runtime.h>
#include <cstdint>
#include <cstddef>

typedef unsigned short u16;
typedef unsigned int   u32;

typedef __bf16 bf8   __attribute__((ext_vector_type(8)));
typedef float  f32x4 __attribute__((ext_vector_type(4)));

__device__ __forceinline__ float b2f(u16 v) {
  union { u32 i; float f; } c; c.i = ((u32)v) << 16; return c.f;
}
__device__ __forceinline__ u16 f2b(float f) {
  union { u32 i; float f; } c; c.f = f;
  u32 x = c.i;
  u32 r = (x + 0x7FFFu + ((x >> 16) & 1u)) >> 16;
  return (u16)r;
}
__device__ __forceinline__ float sigf(float x) { return 1.0f / (1.0f + __expf(-x)); }
__device__ __forceinline__ float tanhfast(float x) { return 2.0f * sigf(2.0f * x) - 1.0f; }

// convert 8 consecutive floats to a bf16x8 fragment (RNE)
__device__ __forceinline__ bf8 cvt8(const float* __restrict__ p) {
  f32x4 lo = *(const f32x4*)p;
  f32x4 hi = *(const f32x4*)(p + 4);
  union { u16 s[8]; bf8 v; } c;
#pragma unroll
  for (int i = 0; i < 4; ++i) { c.s[i] = f2b(lo[i]); c.s[4 + i] = f2b(hi[i]); }
  return c.v;
}

// async 16B global -> LDS (dest = wave-uniform base + lane*16)
__device__ __forceinline__ void ld_lds16(const u16* g, u16* l) {
  __builtin_amdgcn_global_load_lds((const __attribute__((address_space(1))) void*)g,
                                   (__attribute__((address_space(3))) void*)l, 16, 0, 0);
}

#define CSR_STRIDE 80

// ---- weight repack: W fp32 [K x 128] -> Bt bf16 in MFMA-fragment order ----
// frag id f = (hh*4+ks)*512 + c*64 + lane ; element j in [0,8):
//   Bt[f*8+j] = bf16( W[(hh*128+ks*32+quad*8+j)*128 + (c*16+ln)] )   (lane=quad*16+ln)
// blocks >= 64 zero the degree-count array instead.
__global__ __launch_bounds__(256) void k_transpose(
    const float* __restrict__ W0, const float* __restrict__ W1,
    const float* __restrict__ W2, const float* __restrict__ W3,
    const float* __restrict__ W4,
    u16* __restrict__ B0, u16* __restrict__ B1, u16* __restrict__ B2,
    u16* __restrict__ B3, u16* __restrict__ B4,
    int* __restrict__ cnt, int N) {
  if (blockIdx.x >= 64) {
    int i = (blockIdx.x - 64) * 256 + threadIdx.x;
    if (i < N) cnt[i] = 0;
    return;
  }
  int t = blockIdx.x * 256 + threadIdx.x;
  const float* in; u16* out; int f;
  if (t < 2048)       { in = W0; out = B0; f = t; }
  else if (t < 4096)  { in = W1; out = B1; f = t - 2048; }
  else if (t < 8192)  { in = W2; out = B2; f = t - 4096; }
  else if (t < 12288) { in = W3; out = B3; f = t - 8192; }
  else                { in = W4; out = B4; f = t - 12288; }
  int ln = f & 15, quad = (f >> 4) & 3, c = (f >> 6) & 7, ks = (f >> 9) & 3, hh = f >> 11;
  int n = c * 16 + ln;
  int k0 = hh * 128 + ks * 32 + quad * 8;
  union { u16 s[8]; uint4 q; } tmp;
#pragma unroll
  for (int j = 0; j < 8; ++j) tmp.s[j] = f2b(in[(size_t)(k0 + j) * 128 + n]);
  *(uint4*)(out + (size_t)f * 8) = tmp.q;
}

// ---------------- CSR build: one pass; cnt doubles as cursor and final degree ----------------
__global__ void k_fill(const int* __restrict__ src, const int* __restrict__ dst,
                       int* __restrict__ cnt, int* __restrict__ csr, int E) {
  int e = blockIdx.x * 256 + threadIdx.x;
  if (e < E) {
    int d = dst[e];
    int pos = atomicAdd(&cnt[d], 1);
    if (pos < CSR_STRIDE) csr[(size_t)d * CSR_STRIDE + pos] = src[e];
  }
}

// ---------------- aggregation: one wave per node, 4 edges x 16-lane x 16B ----------------
// out[d] = postproc( rsqrt(deg+1) * (sum_{s->d} y[s] + y[d]) + bias )
__global__ __launch_bounds__(256) void k_agg(const u16* __restrict__ y,
                                             const int* __restrict__ cnt,
                                             const int* __restrict__ csr,
                                             const float* __restrict__ bias,
                                             u16* __restrict__ out, int relu, int N) {
  int wv = (blockIdx.x * 256 + threadIdx.x) >> 6;
  int lane = threadIdx.x & 63;
  if (wv >= N) return;
  int g = lane >> 4, t = lane & 15;
  const uint4* yq = (const uint4*)y;        // 16 uint4 per 128-feat bf16 row
  int deg = cnt[wv];
  int degc = (deg < 64) ? deg : 64;
  long base = (long)wv * CSR_STRIDE;
  int myidx = (lane < degc) ? csr[base + lane] : 0;

  float a[8];
#pragma unroll
  for (int j = 0; j < 8; ++j) a[j] = 0.0f;

  for (int b = 0; b < degc; b += 8) {
    int e0 = b + g, e1 = b + 4 + g;
    int s0 = __shfl(myidx, (e0 < degc) ? e0 : 0, 64);
    int s1 = __shfl(myidx, (e1 < degc) ? e1 : 0, 64);
    uint4 v0 = yq[(size_t)s0 * 16 + t];
    uint4 v1 = yq[(size_t)s1 * 16 + t];
    if (e0 < degc) {
      const u32* w = (const u32*)&v0;
#pragma unroll
      for (int i = 0; i < 4; ++i) { a[2*i] += b2f((u16)(w[i] & 0xFFFF)); a[2*i+1] += b2f((u16)(w[i] >> 16)); }
    }
    if (e1 < degc) {
      const u32* w = (const u32*)&v1;
#pragma unroll
      for (int i = 0; i < 4; ++i) { a[2*i] += b2f((u16)(w[i] & 0xFFFF)); a[2*i+1] += b2f((u16)(w[i] >> 16)); }
    }
  }
  // cross-group reduction: groups 0..3 hold partial sums of the same feature slice
#pragma unroll
  for (int j = 0; j < 8; ++j) {
    a[j] += __shfl_xor(a[j], 16, 64);
    a[j] += __shfl_xor(a[j], 32, 64);
  }
  if (g == 0) {
    // rare tail deg in (64, 80): add serially (16 lanes do full rows)
    int degt = (deg < CSR_STRIDE) ? deg : CSR_STRIDE;
    for (int p = 64; p < degt; ++p) {
      int s = csr[base + p];
      uint4 v = yq[(size_t)s * 16 + t];
      const u32* w = (const u32*)&v;
#pragma unroll
      for (int i = 0; i < 4; ++i) { a[2*i] += b2f((u16)(w[i] & 0xFFFF)); a[2*i+1] += b2f((u16)(w[i] >> 16)); }
    }
    // self-loop
    uint4 sv = yq[(size_t)wv * 16 + t];
    const u32* w = (const u32*)&sv;
#pragma unroll
    for (int i = 0; i < 4; ++i) { a[2*i] += b2f((u16)(w[i] & 0xFFFF)); a[2*i+1] += b2f((u16)(w[i] >> 16)); }
    float di = rsqrtf((float)deg + 1.0f);
    f32x4 b0 = *(const f32x4*)(bias + t * 8);
    f32x4 b1 = *(const f32x4*)(bias + t * 8 + 4);
    union { u16 s[8]; uint4 q; } o;
#pragma unroll
    for (int j = 0; j < 8; ++j) {
      float r = di * a[j] + ((j < 4) ? b0[j] : b1[j - 4]);
      if (relu) r = fmaxf(r, 0.0f);
      o.s[j] = f2b(r);
    }
    ((uint4*)out)[(size_t)wv * 16 + t] = o.q;
  }
}

// ---------------- layer GEMM: y[M,128] = bf16( (A[M,128] @ W) * rsqrt(deg+1)[row] ) ----------------
template <bool AF>   // A is fp32 (convert) or bf16
__global__ __launch_bounds__(256) void k_gemm(
    const void* __restrict__ Av,
    const u16* __restrict__ Bt,          // fragment-ordered, 16384 u16
    const int* __restrict__ cnt,
    u16* __restrict__ outb, int M) {
  __shared__ __align__(16) u16 bs[16384];
  int tid = threadIdx.x;
  int lane = tid & 63, wave = tid >> 6;
  int ln = lane & 15, quad = lane >> 4;
  int rowbase = blockIdx.x * 64 + wave * 16;
  int rowA = rowbase + ln;
  long rA = (rowA < M) ? rowA : (M - 1);

  {
    const u16* g = Bt + wave * 4096 + lane * 8;
    u16* l = bs + wave * 4096;
#pragma unroll
    for (int i = 0; i < 8; ++i) ld_lds16(g + i * 512, l + i * 512);
  }

  bf8 af[4];
#pragma unroll
  for (int ks = 0; ks < 4; ++ks) {
    int kk = ks * 32 + quad * 8;
    if (AF) af[ks] = cvt8((const float*)Av + rA * 128 + kk);
    else    af[ks] = *(const bf8*)((const u16*)Av + rA * 128 + kk);
  }

  f32x4 acc[8];
#pragma unroll
  for (int c = 0; c < 8; ++c) { acc[c][0] = 0.f; acc[c][1] = 0.f; acc[c][2] = 0.f; acc[c][3] = 0.f; }

  __syncthreads();   // drains the async LDS DMA
#pragma unroll
  for (int ks = 0; ks < 4; ++ks) {
#pragma unroll
    for (int c = 0; c < 8; ++c) {
      bf8 bfr = *(const bf8*)(bs + ks * 4096 + c * 512 + lane * 8);
      acc[c] = __builtin_amdgcn_mfma_f32_16x16x32_bf16(af[ks], bfr, acc[c], 0, 0, 0);
    }
  }

  int rb = rowbase + quad * 4;
  float rs[4];
#pragma unroll
  for (int r = 0; r < 4; ++r) {
    int row = rb + r;
    rs[r] = (row < M) ? rsqrtf((float)cnt[row] + 1.0f) : 0.0f;
  }
#pragma unroll
  for (int c = 0; c < 8; ++c) {
    int col = c * 16 + ln;
#pragma unroll
    for (int r = 0; r < 4; ++r) {
      int row = rb + r;
      if (row < M) outb[(size_t)row * 128 + col] = f2b(acc[c][r] * rs[r]);
    }
  }
}

// ---------------- fused GRU v10: N-SPLIT waves + lgkm-drained barriers (race fix) ----
// out = (1-u)*h + u*tanh([emb | sig(r)*h] @ Wc + bc); u = sig([emb|h]@Wz+bz)
// v9 structure (2x2 wave grid over 32 rows x 128 cols; 16r x 64c per wave; 6252 waves;
// thin 8KB chunks, 3-slot ring, counted vmcnt) with the v9 CORRECTNESS FIX:
//   every barrier wait is now `s_waitcnt vmcnt(N) lgkmcnt(0)` + s_barrier. v9's
//   vmcnt-only waits let a wave enter the barrier with the PREVIOUS iteration's
//   ds_reads issued-but-unserviced (hipcc sinks the consuming register-only MFMAs past
//   the asm, rule #18, taking their lgkm waits along); the refill DMA one iteration
//   later (slot (t+2)%3 = slot last read at t-1) then overwrites LDS under a queued
//   read -> v9's absmax 1.3. With lgkmcnt(0) drained pre-barrier, every wave's reads
//   are architecturally complete (results in registers) before any refill issues; a
//   sunk MFMA reads registers, not LDS, so it is then harmless. Counted-vmcnt prefetch
//   is preserved. (R6 shared this window and passed by timing; v9's 4-MFMA phases
//   shrank the window 2x and exposed it.)
// Slot liveness (unchanged): chunk k staged at iter k-2 into slot (k-2)%3, read at
// iter k from (k+1)%3 — same slot (differ by 3). LDS 32 KB; launch_bounds (256,2).
__global__ __launch_bounds__(256, 2) void k_gru(
    const u16* __restrict__ emb, const float* __restrict__ h,
    const u16* __restrict__ Btz, const u16* __restrict__ Btr, const u16* __restrict__ Btc,
    const float* __restrict__ bz, const float* __restrict__ br, const float* __restrict__ bc,
    float* __restrict__ out, int M) {
  __shared__ __align__(16) u16 lds[16384];   // 24 KB ring + 8 KB at = 32 KB
  int tid = threadIdx.x;
  int lane = tid & 63, wave = tid >> 6;
  int ln = lane & 15, quad = lane >> 4;
  int wrow  = (wave >> 1) * 16;              // row-half within block (0|16)
  int cbase = (wave & 1) * 4;                // col-half: c-frags [cbase, cbase+4)
  int rowbase = blockIdx.x * 32 + wrow;
  int rowA = rowbase + ln;
  long rA = (rowA < M) ? rowA : (M - 1);
  int rb = rowbase + quad * 4;
  u16* const at = lds + 12288;               // 32x128 rh tile, block-shared, XOR-swizzled

  // stage thin zr chunk t (8 KB: matrix t&1, ks t>>1) into ring slot s: 2 DMA instrs/wave
  auto stage_zr = [&](int t, int s) {
    const u16* src = ((t & 1) ? Btr : Btz) + (t >> 1) * 4096;
#pragma unroll
    for (int i = 0; i < 2; ++i) {
      int off = (wave * 2 + i) * 512;
      ld_lds16(src + off + lane * 8, &lds[s * 4096 + off]);
    }
  };
  // stage c chunk k (8 KB) into ring slot s: 2 DMA instrs/wave
  auto stage_c = [&](int k, int s) {
#pragma unroll
    for (int i = 0; i < 2; ++i) {
      int off = (wave * 2 + i) * 512;
      ld_lds16(Btc + k * 4096 + off + lane * 8, &lds[s * 4096 + off]);
    }
  };

  // A fragments first (their conversions force completion before stages issue)
  bf8 af_e[4], af_h[4];
#pragma unroll
  for (int ks = 0; ks < 4; ++ks)
    af_e[ks] = *(const bf8*)(emb + rA * 128 + ks * 32 + quad * 8);
#pragma unroll
  for (int ks = 0; ks < 4; ++ks)
    af_h[ks] = cvt8(h + rA * 128 + ks * 32 + quad * 8);

  // depth-2 prefetch
  stage_zr(0, 0);
  stage_zr(1, 1);

  f32x4 accz[4], accr[4];
#pragma unroll
  for (int c = 0; c < 4; ++c) {
    accz[c][0] = 0.f; accz[c][1] = 0.f; accz[c][2] = 0.f; accz[c][3] = 0.f;
    accr[c][0] = 0.f; accr[c][1] = 0.f; accr[c][2] = 0.f; accr[c][3] = 0.f;
  }

  // z/r pass: 16 thin chunks (z,r alternating per ks); wave consumes its col-half only
#pragma unroll
  for (int t = 0; t < 16; ++t) {
    if (t < 15) asm volatile("s_waitcnt vmcnt(2) lgkmcnt(0)\n\ts_barrier" ::: "memory");
    else        asm volatile("s_waitcnt vmcnt(0) lgkmcnt(0)\n\ts_barrier" ::: "memory");
    if (t < 14) stage_zr(t + 2, (t + 2) % 3);
    int ks = t >> 1;
    bf8 af = (ks < 4) ? af_e[ks] : af_h[ks - 4];
    int s = t % 3;
    f32x4* acc = (t & 1) ? accr : accz;   // t unrolled -> static selection
#pragma unroll
    for (int c = 0; c < 4; ++c) {
      bf8 bfr = *(const bf8*)(&lds[s * 4096 + ((cbase + c) * 64 + lane) * 8]);
      acc[c] = __builtin_amdgcn_mfma_f32_16x16x32_bf16(af, bfr, acc[c], 0, 0, 0);
    }
  }

  // c chunks 0,1 into slots 1,2 (free: slot-1/2 reads [t=13,t=14] were lgkm-drained at
  // the t=15 barrier; t=15 itself reads slot 0). DMA hides under hc loads + epilogue.
  stage_c(0, 1);
  stage_c(1, 2);

  // h at C-layout positions (wave's col-half) — kept in registers
  f32x4 hc[4];
#pragma unroll
  for (int c = 0; c < 4; ++c) {
    int col = (cbase + c) * 16 + ln;
#pragma unroll
    for (int r = 0; r < 4; ++r) {
      int row = rb + r;
      hc[c][r] = (row < M) ? h[(size_t)row * 128 + col] : 0.0f;
    }
  }

  // u = sigmoid(accz+bz); rh = sigmoid(accr+br)*h -> block-shared at tile (XOR swizzle)
#pragma unroll
  for (int c = 0; c < 4; ++c) {
    int col = (cbase + c) * 16 + ln;
    float bzc = bz[col], brc = br[col];
#pragma unroll
    for (int r = 0; r < 4; ++r) {
      float uu = sigf(accz[c][r] + bzc);
      float rr = sigf(accr[c][r] + brc);
      accz[c][r] = uu;                       // keep u in registers
      int wl = wrow + quad * 4 + r;          // block-local row 0..31
      int idx = (wl * 128 + col) ^ ((wl & 7) << 3);
      at[idx] = f2b(rr * hc[c][r]);
      accr[c][r] = 0.0f;                     // accr becomes candidate accumulator
    }
  }
  // col-half exchange: all waves' rh quadrants visible before full-width readback
  asm volatile("s_waitcnt lgkmcnt(0)\n\ts_barrier" ::: "memory");

  bf8 af_at[4];
#pragma unroll
  for (int ks = 0; ks < 4; ++ks) {
    int wl = wrow + ln;
    int idx = (wl * 128 + ks * 32 + quad * 8) ^ ((wl & 7) << 3);
    af_at[ks] = *(const bf8*)(&at[idx]);
  }

  // candidate pass: 8 chunks, cslot(j) = (j+1)%3
#pragma unroll
  for (int j = 0; j < 8; ++j) {
    if (j < 7) asm volatile("s_waitcnt vmcnt(2) lgkmcnt(0)\n\ts_barrier" ::: "memory");
    else       asm volatile("s_waitcnt vmcnt(0) lgkmcnt(0)\n\ts_barrier" ::: "memory");
    if (j < 6) stage_c(j + 2, j % 3);        // slot j%3: reads (iter j-1) lgkm-drained
    bf8 af = (j < 4) ? af_e[j] : af_at[j - 4];
    int s = (j + 1) % 3;
#pragma unroll
    for (int c = 0; c < 4; ++c) {
      bf8 bfr = *(const bf8*)(&lds[s * 4096 + ((cbase + c) * 64 + lane) * 8]);
      accr[c] = __builtin_amdgcn_mfma_f32_16x16x32_bf16(af, bfr, accr[c], 0, 0, 0);
    }
  }

  // epilogue: out = (1-u)*h + u*tanh(accc + bc)   (wave's 16r x 64c quadrant)
#pragma unroll
  for (int c = 0; c < 4; ++c) {
    int col = (cbase + c) * 16 + ln;
    float bcc = bc[col];
#pragma unroll
    for (int r = 0; r < 4; ++r) {
      int row = rb + r;
      if (row < M) {
        float cd = tanhfast(accr[c][r] + bcc);
        float uu = accz[c][r];
        out[(size_t)row * 128 + col] = (1.0f - uu) * hc[c][r] + uu * cd;
      }
    }
  }
}

extern "C" void kernel_launch(void* const* d_in, const int* in_sizes, int n_in,
                              void* d_out, int out_size, void* d_ws, size_t ws_size,
                              hipStream_t stream) {
  const float* x     = (const float*)d_in[0];
  const float* h     = (const float*)d_in[1];
  const int*   ei    = (const int*)d_in[2];
  const float* W_in  = (const float*)d_in[3];
  const float* b_in  = (const float*)d_in[4];
  const float* W_hid = (const float*)d_in[5];
  const float* b_hid = (const float*)d_in[6];
  const float* W_z   = (const float*)d_in[7];
  const float* b_z   = (const float*)d_in[8];
  const float* W_r   = (const float*)d_in[9];
  const float* b_r   = (const float*)d_in[10];
  const float* W_c   = (const float*)d_in[11];
  const float* b_c   = (const float*)d_in[12];

  const int N = in_sizes[0] / 128;
  const int E = in_sizes[2] / 2;
  const int* src = ei;
  const int* dst = ei + E;

  char* p = (char*)d_ws;
  auto carve = [&](size_t bytes) { char* r = p; p += (bytes + 255) & ~(size_t)255; return r; };
  u16* Bt_in   = (u16*)carve((size_t)16384 * 2);
  u16* Bt_hid  = (u16*)carve((size_t)16384 * 2);
  u16* Bt_z    = (u16*)carve((size_t)32768 * 2);
  u16* Bt_r    = (u16*)carve((size_t)32768 * 2);
  u16* Bt_c    = (u16*)carve((size_t)32768 * 2);
  int* cnt  = (int*)carve((size_t)N * 4);
  int* csr  = (int*)carve((size_t)N * CSR_STRIDE * 4);
  u16* y    = (u16*)carve((size_t)N * 128 * 2);    // bf16 intermediates
  u16* h1   = (u16*)carve((size_t)N * 128 * 2);
  u16* emb  = (u16*)carve((size_t)N * 128 * 2);

  int gN = (N + 255) / 256;
  int gE = (E + 255) / 256;
  int gG = (N + 63) / 64;      // GEMM: 64 rows per block
  int gGru = (N + 31) / 32;    // GRU: 32 rows per block (2x2 row/col wave split)
  int gA = (N + 3) / 4;        // AGG: 4 waves (nodes) per block

  k_transpose<<<64 + gN, 256, 0, stream>>>(W_in, W_hid, W_z, W_r, W_c,
                                           Bt_in, Bt_hid, Bt_z, Bt_r, Bt_c, cnt, N);
  k_fill<<<gE, 256, 0, stream>>>(src, dst, cnt, csr, E);

  // layer 1: y = (x @ W_in) * dinv ; h1 = relu(dinv * agg(y) + b_in)
  k_gemm<true><<<gG, 256, 0, stream>>>(x, Bt_in, cnt, y, N);
  k_agg<<<gA, 256, 0, stream>>>(y, cnt, csr, b_in, h1, 1, N);
  // layer 2: y = (h1 @ W_hid) * dinv ; emb = dinv * agg(y) + b_hid
  k_gemm<false><<<gG, 256, 0, stream>>>(h1, Bt_hid, cnt, y, N);
  k_agg<<<gA, 256, 0, stream>>>(y, cnt, csr, b_hid, emb, 0, N);
  // fused GRU: N-split waves, lgkm-drained barriers
  k_gru<<<gGru, 256, 0, stream>>>(emb, h, Bt_z, Bt_r, Bt_c, b_z, b_r, b_c, (float*)d_out, N);
}